// Round 10
// baseline (629.920 us; speedup 1.0000x reference)
//
#include <hip/hip_runtime.h>

#define NSEQ   4096
#define TSTEPS 512
#define FIN    5
#define HID    64
#define SPB    16     // 2 groups x 8 seqs, software-pipelined
#define BLK    256
#define GP     68     // gt pitch (floats): 4*GP % 32 == 16 -> quads split bank halves

// Neutral names — do NOT reuse HIP vector-type names like short8 (R4 crash)
typedef __attribute__((ext_vector_type(8))) short bsh8;    // 8 bf16 in 4 VGPRs
typedef __attribute__((ext_vector_type(4))) float f32x4;   // MFMA accumulator

#define MFMA16(A, B, C) __builtin_amdgcn_mfma_f32_16x16x32_bf16((A), (B), (C), 0, 0, 0)

struct Frag2 { bsh8 hi; bsh8 lo; };

__device__ __forceinline__ unsigned short bf16hi_rn(float x) {
    unsigned u = __float_as_uint(x);
    return (unsigned short)((u + 0x7fffu + ((u >> 16) & 1u)) >> 16);
}
__device__ __forceinline__ void split_bf16(float v, unsigned short& h, unsigned short& l) {
    h = bf16hi_rn(v);
    float hf_ = __uint_as_float(((unsigned)h) << 16);
    l = bf16hi_rn(v - hf_);
}

__device__ __forceinline__ float fast_sigmoid(float x) {
    return __builtin_amdgcn_rcpf(1.0f + __expf(-x));
}
__device__ __forceinline__ float fast_tanh(float x) {
    return 1.0f - 2.0f * __builtin_amdgcn_rcpf(1.0f + __expf(2.0f * x));
}

// B-fragment (weights SPLIT hi/lo — systematic weight error stays ~2^-17)
__device__ __forceinline__ Frag2 load_whh_frag(const float* __restrict__ Whh, int gate, int k) {
    const float* p = Whh + gate * HID + k;
    Frag2 r;
#pragma unroll
    for (int j = 0; j < 8; ++j) {
        unsigned short h, l;
        split_bf16(p[j], h, l);
        r.hi[j] = (short)h; r.lo[j] = (short)l;
    }
    return r;
}
__device__ __forceinline__ Frag2 load_wih_frag(const float* __restrict__ Wih, int gate, int quad) {
    Frag2 r;
#pragma unroll
    for (int j = 0; j < 8; ++j) { r.hi[j] = 0; r.lo[j] = 0; }
    if (quad == 0) {
#pragma unroll
        for (int j = 0; j < FIN; ++j) {
            unsigned short h, l;
            split_bf16(Wih[gate * FIN + j], h, l);
            r.hi[j] = (short)h; r.lo[j] = (short)l;
        }
    }
    return r;
}

// Two-group pipelined MFMA LSTM (R7-R9 lesson: intra-block waves are
// phase-locked by barriers — overlap must come from independent work INSIDE
// a wave). 16 seqs = 2 groups of 8 (M=8 half-tiles). Per step:
//   phase A: MFMA-G0(t) [24 MFMA] overlapped with epilogue-G1(t-1) [VALU]
//   phase B: MFMA-G1(t) overlapped with epilogue-G0(t)
// The epilogue in a phase is independent of that phase's MFMAs -> the wave
// issues trans VALU while its MFMAs drain the matrix pipe. Preacts cross via
// gt (pitch 68 -> conflict-free writes / 2-way-free reads); epilogue lanes
// remap to (seq=tid>>5, unit=tid&31,+32) = 2 full cells/lane (no exec-mask
// waste). A rows 8-15 duplicate rows 0-7 (C rows 8-15 ignored; D row m only
// depends on A row m).
__global__ __launch_bounds__(BLK)
void lstm_kernel(const float* __restrict__ feat,
                 const float* __restrict__ Wih,
                 const float* __restrict__ Whh,
                 const float* __restrict__ bih,
                 const float* __restrict__ bhh,
                 const float* __restrict__ Wd,
                 const float* __restrict__ bd,
                 float* __restrict__ pred,
                 float* __restrict__ accums) {
    __shared__ bsh8  aG[2][2][8][9];     // [group][buf][seq-in-group][kvec] (4.6 KB)
    __shared__ bsh8  xb[2][64][SPB];     // x bf16, chunk double buffer (32 KB)
    __shared__ float gt[2][4][8][GP];    // preact exchange [group][gate][seq][unit] (17.4 KB)
    __shared__ float hf[SPB][HID + 1];   // final h fp32 for pred tail
    __shared__ float pf[SPB][17];        // pred partials

    const int tid  = threadIdx.x;
    const int w    = tid >> 6;           // wave 0..3
    const int lane = tid & 63;
    const int col  = lane & 15;          // MFMA A/C column index
    const int quad = lane >> 4;
    const int u    = 16 * w + col;       // M-side unit
    const int es   = tid >> 5;           // E-side seq-in-group 0..7
    const int eu   = tid & 31;           // E-side unit (and eu+32)
    const int seq0 = blockIdx.x * SPB;

    if (blockIdx.x == 0 && tid < 4) accums[tid] = 0.0f;   // loss accumulators

    // ---- persistent B fragments (named structs — R1/R2 spill lessons) ----
    const int g0 = 0 * HID + u, g1 = 1 * HID + u, g2 = 2 * HID + u, g3 = 3 * HID + u;
    Frag2 b00 = load_whh_frag(Whh, g0, quad * 8);
    Frag2 b01 = load_whh_frag(Whh, g0, 32 + quad * 8);
    Frag2 b02 = load_wih_frag(Wih, g0, quad);
    Frag2 b10 = load_whh_frag(Whh, g1, quad * 8);
    Frag2 b11 = load_whh_frag(Whh, g1, 32 + quad * 8);
    Frag2 b12 = load_wih_frag(Wih, g1, quad);
    Frag2 b20 = load_whh_frag(Whh, g2, quad * 8);
    Frag2 b21 = load_whh_frag(Whh, g2, 32 + quad * 8);
    Frag2 b22 = load_wih_frag(Wih, g2, quad);
    Frag2 b30 = load_whh_frag(Whh, g3, quad * 8);
    Frag2 b31 = load_whh_frag(Whh, g3, 32 + quad * 8);
    Frag2 b32 = load_wih_frag(Wih, g3, quad);

    const float bi  = bih[g0] + bhh[g0];
    const float bf_ = bih[g1] + bhh[g1];
    const float bg  = bih[g2] + bhh[g2];
    const float bo  = bih[g3] + bhh[g3];

    // zero all aG (288 vectors)
    {
        bsh8 z = {0, 0, 0, 0, 0, 0, 0, 0};
        bsh8* p = &aG[0][0][0][0];
        for (int i = tid; i < 2 * 2 * 8 * 9; i += BLK) p[i] = z;
    }
    // stage chunk 0 (4 items/lane)
#pragma unroll
    for (int it = 0; it < (64 * SPB) / BLK; ++it) {
        int idx = tid + it * BLK;
        int t2  = idx >> 4;
        int s   = idx & 15;
        const float* xp = feat + (size_t)(seq0 + s) * (TSTEPS * FIN) + t2 * FIN;
        bsh8 v = {0, 0, 0, 0, 0, 0, 0, 0};
#pragma unroll
        for (int j = 0; j < FIN; ++j) v[j] = (short)bf16hi_rn(xp[j]);
        xb[0][t2][s] = v;
    }
    __syncthreads();

    f32x4 acc0, acc1, acc2, acc3;
    float c00 = 0.f, c01 = 0.f, c10 = 0.f, c11 = 0.f;

// 24 MFMAs for group G step t (A rows = col&7 duplicates; x seeded w/ bias)
#define MSTEP(G)                                                           \
    {                                                                      \
        acc0 = (f32x4){bi,  bi,  bi,  bi };                                \
        acc1 = (f32x4){bf_, bf_, bf_, bf_};                                \
        acc2 = (f32x4){bg,  bg,  bg,  bg };                                \
        acc3 = (f32x4){bo,  bo,  bo,  bo };                                \
        bsh8 ax = xb[cb][tt][(G) * 8 + (col & 7)];                         \
        acc0 = MFMA16(ax, b02.hi, acc0); acc0 = MFMA16(ax, b02.lo, acc0);  \
        acc1 = MFMA16(ax, b12.hi, acc1); acc1 = MFMA16(ax, b12.lo, acc1);  \
        acc2 = MFMA16(ax, b22.hi, acc2); acc2 = MFMA16(ax, b22.lo, acc2);  \
        acc3 = MFMA16(ax, b32.hi, acc3); acc3 = MFMA16(ax, b32.lo, acc3);  \
        bsh8 ah0 = aG[G][buf][col & 7][quad];                              \
        bsh8 ah1 = aG[G][buf][col & 7][4 + quad];                          \
        acc0 = MFMA16(ah0, b00.hi, acc0); acc0 = MFMA16(ah1, b01.hi, acc0);\
        acc1 = MFMA16(ah0, b10.hi, acc1); acc1 = MFMA16(ah1, b11.hi, acc1);\
        acc2 = MFMA16(ah0, b20.hi, acc2); acc2 = MFMA16(ah1, b21.hi, acc2);\
        acc3 = MFMA16(ah0, b30.hi, acc3); acc3 = MFMA16(ah1, b31.hi, acc3);\
        acc0 = MFMA16(ah0, b00.lo, acc0); acc0 = MFMA16(ah1, b01.lo, acc0);\
        acc1 = MFMA16(ah0, b10.lo, acc1); acc1 = MFMA16(ah1, b11.lo, acc1);\
        acc2 = MFMA16(ah0, b20.lo, acc2); acc2 = MFMA16(ah1, b21.lo, acc2);\
        acc3 = MFMA16(ah0, b30.lo, acc3); acc3 = MFMA16(ah1, b31.lo, acc3);\
    }

// export preacts (quads 0,1 carry rows 0..7; conflict-free: quad1 +16 banks)
#define GTWR(G)                                                            \
    if (quad < 2) {                                                        \
        _Pragma("unroll")                                                  \
        for (int r = 0; r < 4; ++r) {                                      \
            gt[G][0][quad * 4 + r][u] = acc0[r];                           \
            gt[G][1][quad * 4 + r][u] = acc1[r];                           \
            gt[G][2][quad * 4 + r][u] = acc2[r];                           \
            gt[G][3][quad * 4 + r][u] = acc3[r];                           \
        }                                                                  \
    }

// epilogue for group G: 2 cells (es, eu) and (es, eu+32)
#define EPILOG(G, CA, CB, DSTROW, WHF)                                     \
    {                                                                      \
        float vi0 = gt[G][0][es][eu],      vf0 = gt[G][1][es][eu];         \
        float vg0 = gt[G][2][es][eu],      vo0 = gt[G][3][es][eu];         \
        float vi1 = gt[G][0][es][eu + 32], vf1 = gt[G][1][es][eu + 32];    \
        float vg1 = gt[G][2][es][eu + 32], vo1 = gt[G][3][es][eu + 32];    \
        float gi0 = fast_sigmoid(vi0), gf0 = fast_sigmoid(vf0);            \
        float gg0 = fast_tanh(vg0),    go0 = fast_sigmoid(vo0);            \
        float gi1 = fast_sigmoid(vi1), gf1 = fast_sigmoid(vf1);            \
        float gg1 = fast_tanh(vg1),    go1 = fast_sigmoid(vo1);            \
        CA = gf0 * CA + gi0 * gg0;                                         \
        CB = gf1 * CB + gi1 * gg1;                                         \
        float hh0 = go0 * fast_tanh(CA);                                   \
        float hh1 = go1 * fast_tanh(CB);                                   \
        ((unsigned short*)(DSTROW))[eu]      = bf16hi_rn(hh0);             \
        ((unsigned short*)(DSTROW))[eu + 32] = bf16hi_rn(hh1);             \
        if (WHF) { hf[(G) * 8 + es][eu]      = hh0;                        \
                   hf[(G) * 8 + es][eu + 32] = hh1; }                      \
    }

    for (int t = 0; t < TSTEPS; ++t) {
        const int tt  = t & 63;
        const int cb  = (t >> 6) & 1;
        const int buf = t & 1;
        const int nb  = buf ^ 1;

        // ================= PHASE A: MFMA-G0(t) || epi-G1(t-1) =================
        MSTEP(0)
        if (t > 0) {
            // h_G1(t-1) -> aG[1][t&1], read by MSTEP(1) after the barrier
            EPILOG(1, c10, c11, &aG[1][buf][es][0], false)
        }
        GTWR(0)
        if (tt == 0 && t + 64 < TSTEPS) {   // stage next chunk into xb[cb^1]
            int t0n = t + 64;
#pragma unroll
            for (int it = 0; it < (64 * SPB) / BLK; ++it) {
                int idx = tid + it * BLK;
                int t2  = idx >> 4;
                int s   = idx & 15;
                const float* xp = feat + (size_t)(seq0 + s) * (TSTEPS * FIN)
                                       + (t0n + t2) * FIN;
                bsh8 v = {0, 0, 0, 0, 0, 0, 0, 0};
#pragma unroll
                for (int j = 0; j < FIN; ++j) v[j] = (short)bf16hi_rn(xp[j]);
                xb[cb ^ 1][t2][s] = v;
            }
        }
        __syncthreads();

        // ================= PHASE B: MFMA-G1(t) || epi-G0(t) =================
        MSTEP(1)
        EPILOG(0, c00, c01, &aG[0][nb][es][0], t == TSTEPS - 1)
        GTWR(1)
        __syncthreads();
    }
    // tail: epi-G1(511) (gt[1] written in last phase B; barrier passed)
    EPILOG(1, c10, c11, &aG[1][0][es][0], true)
    __syncthreads();

    // ---- fused pred head: pred = leaky_relu(h @ Wd^T + bd) ----
    {
        int s  = tid & 15;
        int q4 = tid >> 4;           // 16 unit-groups of 4
        int j0 = q4 * 4;
        float part = hf[s][j0] * Wd[j0] + hf[s][j0 + 1] * Wd[j0 + 1]
                   + hf[s][j0 + 2] * Wd[j0 + 2] + hf[s][j0 + 3] * Wd[j0 + 3];
        pf[s][q4] = part;
    }
    __syncthreads();
    if (tid < SPB) {
        float sum = bd[0];
#pragma unroll
        for (int j = 0; j < 16; ++j) sum += pf[tid][j];
        float p = (sum >= 0.0f) ? sum : 0.2f * sum;
        pred[seq0 + tid] = p;
    }
#undef MSTEP
#undef GTWR
#undef EPILOG
}

// fused losses: every block does a 16-i rank slice; block 0 also does reg MSE
__global__ __launch_bounds__(256)
void loss_kernel(const float* __restrict__ pred,
                 const float* __restrict__ ret,
                 const int* __restrict__ mask,
                 float* __restrict__ accums) {
    __shared__ float sp[NSEQ];
    __shared__ float sg[NSEQ];
    __shared__ float sq[NSEQ];
    int tid = threadIdx.x;
    for (int idx = tid; idx < NSEQ; idx += 256) {
        sp[idx] = pred[idx];
        sg[idx] = ret[idx];
        sq[idx] = (mask[idx] != 0) ? 1.0f : 0.0f;
    }
    __syncthreads();

    if (blockIdx.x == 0) {   // regression loss partials
        float v = 0.0f, m = 0.0f;
        for (int j = tid; j < NSEQ; j += 256) {
            float mj = sq[j];
            float d  = sp[j] - sg[j];
            v += d * d * mj;
            m += mj;
        }
#pragma unroll
        for (int off = 32; off > 0; off >>= 1) {
            v += __shfl_down(v, off, 64);
            m += __shfl_down(m, off, 64);
        }
        if ((tid & 63) == 0) {
            atomicAdd(&accums[0], v);
            atomicAdd(&accums[1], m);
        }
    }

    int iloc = tid >> 4;
    int jp   = tid & 15;
    int i    = blockIdx.x * 16 + iloc;
    float pi = sp[i], gi = sg[i], qi = sq[i];
    float sum = 0.0f;
    for (int j = jp; j < NSEQ; j += 16) {
        float t = -(sp[j] - pi) * (sg[j] - gi);
        sum += fmaxf(t, 0.0f) * sq[j];
    }
    sum *= qi;
#pragma unroll
    for (int off = 32; off > 0; off >>= 1) sum += __shfl_down(sum, off, 64);
    __shared__ float wsum[4];
    if ((tid & 63) == 0) wsum[tid >> 6] = sum;
    __syncthreads();
    if (tid == 0) atomicAdd(&accums[2], wsum[0] + wsum[1] + wsum[2] + wsum[3]);
}

__global__ void final_kernel(const float* __restrict__ accums,
                             float* __restrict__ out) {
    float reg  = accums[0] / (accums[1] + 1e-8f);
    float rank = accums[2] / 16777216.0f;   // N*N
    out[NSEQ + 0] = reg + rank;
    out[NSEQ + 1] = reg;
    out[NSEQ + 2] = rank;
}

extern "C" void kernel_launch(void* const* d_in, const int* in_sizes, int n_in,
                              void* d_out, int out_size, void* d_ws, size_t ws_size,
                              hipStream_t stream) {
    const float* feat = (const float*)d_in[0];
    const float* ret  = (const float*)d_in[1];
    const int*   mask = (const int*)d_in[2];
    const float* Wih  = (const float*)d_in[3];
    const float* Whh  = (const float*)d_in[4];
    const float* bih  = (const float*)d_in[5];
    const float* bhh  = (const float*)d_in[6];
    const float* Wd   = (const float*)d_in[7];
    const float* bd   = (const float*)d_in[8];
    float* out    = (float*)d_out;
    float* accums = (float*)d_ws;            // [0..3] loss partials

    lstm_kernel<<<NSEQ / SPB, BLK, 0, stream>>>(feat, Wih, Whh, bih, bhh,
                                                Wd, bd, out, accums);
    loss_kernel<<<NSEQ / 16, 256, 0, stream>>>(out, ret, mask, accums);
    final_kernel<<<1, 1, 0, stream>>>(accums, out);
}

// Round 11
// 502.351 us; speedup vs baseline: 1.2539x; 1.2539x over previous
//
#include <hip/hip_runtime.h>

#define NSEQ   4096
#define TSTEPS 512
#define FIN    5
#define HID    64
#define SPB    8      // 8 seqs/block -> grid 512 = 2 independent blocks per CU
#define BLK    256

// Neutral names — do NOT reuse HIP vector-type names like short8 (R4 crash)
typedef __attribute__((ext_vector_type(8))) short bsh8;    // 8 bf16 in 4 VGPRs
typedef __attribute__((ext_vector_type(4))) float f32x4;   // MFMA accumulator

#define MFMA16(A, B, C) __builtin_amdgcn_mfma_f32_16x16x32_bf16((A), (B), (C), 0, 0, 0)

struct Frag2 { bsh8 hi; bsh8 lo; };

__device__ __forceinline__ unsigned short bf16hi_rn(float x) {
    unsigned u = __float_as_uint(x);
    return (unsigned short)((u + 0x7fffu + ((u >> 16) & 1u)) >> 16);
}
__device__ __forceinline__ void split_bf16(float v, unsigned short& h, unsigned short& l) {
    h = bf16hi_rn(v);
    float hf_ = __uint_as_float(((unsigned)h) << 16);
    l = bf16hi_rn(v - hf_);
}

__device__ __forceinline__ float fast_sigmoid(float x) {
    return __builtin_amdgcn_rcpf(1.0f + __expf(-x));
}
__device__ __forceinline__ float fast_tanh(float x) {
    return 1.0f - 2.0f * __builtin_amdgcn_rcpf(1.0f + __expf(2.0f * x));
}

// B-fragment (weights SPLIT hi/lo — systematic weight error stays ~2^-17)
__device__ __forceinline__ Frag2 load_whh_frag(const float* __restrict__ Whh, int gate, int k) {
    const float* p = Whh + gate * HID + k;
    Frag2 r;
#pragma unroll
    for (int j = 0; j < 8; ++j) {
        unsigned short h, l;
        split_bf16(p[j], h, l);
        r.hi[j] = (short)h; r.lo[j] = (short)l;
    }
    return r;
}
__device__ __forceinline__ Frag2 load_wih_frag(const float* __restrict__ Wih, int gate, int quad) {
    Frag2 r;
#pragma unroll
    for (int j = 0; j < 8; ++j) { r.hi[j] = 0; r.lo[j] = 0; }
    if (quad == 0) {
#pragma unroll
        for (int j = 0; j < FIN; ++j) {
            unsigned short h, l;
            split_bf16(Wih[gate * FIN + j], h, l);
            r.hi[j] = (short)h; r.lo[j] = (short)l;
        }
    }
    return r;
}

// R6 structure, 2 independent blocks per CU (R7-R10 lesson: all intra-block
// overlap schemes fail — waves are barrier-phase-locked, producer-consumer
// stalls on its own MFMA chain. Cross-BLOCK waves have independent barriers
// and fill each other's stall cycles). SPB=8: A rows 8-15 duplicate 0-7
// (D row m depends only on A row m; rows 8-15 of C ignored). Epilogue split
// so every lane owns exactly 2 cells via the C-row duplication:
//   quad q -> seq rows (q&1)*4 + (q>>1)*2 + {0,1}, acc idx (q>>1)*2 + {0,1}
// -> per-wave transcendentals halve vs R6; all rows covered exactly once.
__global__ __launch_bounds__(BLK)
void lstm_kernel(const float* __restrict__ feat,
                 const float* __restrict__ Wih,
                 const float* __restrict__ Whh,
                 const float* __restrict__ bih,
                 const float* __restrict__ bhh,
                 const float* __restrict__ Wd,
                 const float* __restrict__ bd,
                 float* __restrict__ pred,
                 float* __restrict__ accums) {
    __shared__ bsh8  aA[2][SPB][9];     // h bf16, double-buffered (2.3 KB)
    __shared__ bsh8  xb[2][64][SPB];    // x bf16, chunk double buffer (16 KB)
    __shared__ float hf[SPB][HID + 1];  // final h fp32 for pred tail
    __shared__ float pf[SPB][33];       // pred partials

    const int tid  = threadIdx.x;
    const int w    = tid >> 6;          // wave 0..3
    const int lane = tid & 63;
    const int col  = lane & 15;         // MFMA col; A row = col&7
    const int row8 = col & 7;
    const int quad = lane >> 4;
    const int u    = 16 * w + col;      // unit handled by this lane
    const int seq0 = blockIdx.x * SPB;
    // epilogue mapping: 2 cells per lane (see header comment)
    const int ep_r0 = (quad >> 1) * 2;          // acc indices ep_r0, ep_r0+1
    const int ep_s0 = (quad & 1) * 4 + ep_r0;   // seq rows ep_s0, ep_s0+1

    if (blockIdx.x == 0 && tid < 4) accums[tid] = 0.0f;   // loss accumulators

    // ---- persistent B fragments (named structs — R1/R2 spill lessons) ----
    const int g0 = 0 * HID + u, g1 = 1 * HID + u, g2 = 2 * HID + u, g3 = 3 * HID + u;
    Frag2 b00 = load_whh_frag(Whh, g0, quad * 8);
    Frag2 b01 = load_whh_frag(Whh, g0, 32 + quad * 8);
    Frag2 b02 = load_wih_frag(Wih, g0, quad);
    Frag2 b10 = load_whh_frag(Whh, g1, quad * 8);
    Frag2 b11 = load_whh_frag(Whh, g1, 32 + quad * 8);
    Frag2 b12 = load_wih_frag(Wih, g1, quad);
    Frag2 b20 = load_whh_frag(Whh, g2, quad * 8);
    Frag2 b21 = load_whh_frag(Whh, g2, 32 + quad * 8);
    Frag2 b22 = load_wih_frag(Wih, g2, quad);
    Frag2 b30 = load_whh_frag(Whh, g3, quad * 8);
    Frag2 b31 = load_whh_frag(Whh, g3, 32 + quad * 8);
    Frag2 b32 = load_wih_frag(Wih, g3, quad);

    const float bi  = bih[g0] + bhh[g0];
    const float bf_ = bih[g1] + bhh[g1];
    const float bg  = bih[g2] + bhh[g2];
    const float bo  = bih[g3] + bhh[g3];

    // zero both h buffers (2*8*9 = 144 vectors)
    {
        bsh8 z = {0, 0, 0, 0, 0, 0, 0, 0};
        if (tid < 2 * SPB * 9) (&aA[0][0][0])[tid] = z;
    }
    // stage chunk 0 (2 items/lane)
#pragma unroll
    for (int it = 0; it < (64 * SPB) / BLK; ++it) {
        int idx = tid + it * BLK;
        int t2  = idx >> 3;
        int s   = idx & 7;
        const float* xp = feat + (size_t)(seq0 + s) * (TSTEPS * FIN) + t2 * FIN;
        bsh8 v = {0, 0, 0, 0, 0, 0, 0, 0};
#pragma unroll
        for (int j = 0; j < FIN; ++j) v[j] = (short)bf16hi_rn(xp[j]);
        xb[0][t2][s] = v;
    }
    __syncthreads();

    // acc := bias + x-part of step 0 (8 MFMAs)
    f32x4 acc0 = {bi,  bi,  bi,  bi };
    f32x4 acc1 = {bf_, bf_, bf_, bf_};
    f32x4 acc2 = {bg,  bg,  bg,  bg };
    f32x4 acc3 = {bo,  bo,  bo,  bo };
    {
        bsh8 ax = xb[0][0][row8];
        acc0 = MFMA16(ax, b02.hi, acc0); acc0 = MFMA16(ax, b02.lo, acc0);
        acc1 = MFMA16(ax, b12.hi, acc1); acc1 = MFMA16(ax, b12.lo, acc1);
        acc2 = MFMA16(ax, b22.hi, acc2); acc2 = MFMA16(ax, b22.lo, acc2);
        acc3 = MFMA16(ax, b32.hi, acc3); acc3 = MFMA16(ax, b32.lo, acc3);
    }

    float c_[2] = {0.f, 0.f};   // this lane's 2 cells

    for (int t = 0; t < TSTEPS; ++t) {
        const int tt  = t & 63;
        const int buf = t & 1;
        const int nb  = buf ^ 1;
        __syncthreads();   // h(t-1) writes + staged x visible

        // prefetch-stage next chunk (buffer idle for 64 steps)
        if (tt == 0 && t + 64 < TSTEPS) {
            int t0n = t + 64;
            bsh8 (*dst)[SPB] = xb[((t >> 6) + 1) & 1];
#pragma unroll
            for (int it = 0; it < (64 * SPB) / BLK; ++it) {
                int idx = tid + it * BLK;
                int t2  = idx >> 3;
                int s   = idx & 7;
                const float* xp = feat + (size_t)(seq0 + s) * (TSTEPS * FIN)
                                       + (t0n + t2) * FIN;
                bsh8 v = {0, 0, 0, 0, 0, 0, 0, 0};
#pragma unroll
                for (int j = 0; j < FIN; ++j) v[j] = (short)bf16hi_rn(xp[j]);
                dst[t2][s] = v;
            }
        }

        // ---- 16 h-MFMAs (critical path) ----
        bsh8 ah0 = aA[buf][row8][quad];
        bsh8 ah1 = aA[buf][row8][4 + quad];
        acc0 = MFMA16(ah0, b00.hi, acc0); acc0 = MFMA16(ah1, b01.hi, acc0);
        acc1 = MFMA16(ah0, b10.hi, acc1); acc1 = MFMA16(ah1, b11.hi, acc1);
        acc2 = MFMA16(ah0, b20.hi, acc2); acc2 = MFMA16(ah1, b21.hi, acc2);
        acc3 = MFMA16(ah0, b30.hi, acc3); acc3 = MFMA16(ah1, b31.hi, acc3);
        acc0 = MFMA16(ah0, b00.lo, acc0); acc0 = MFMA16(ah1, b01.lo, acc0);
        acc1 = MFMA16(ah0, b10.lo, acc1); acc1 = MFMA16(ah1, b11.lo, acc1);
        acc2 = MFMA16(ah0, b20.lo, acc2); acc2 = MFMA16(ah1, b21.lo, acc2);
        acc3 = MFMA16(ah0, b30.lo, acc3); acc3 = MFMA16(ah1, b31.lo, acc3);

        // ---- epilogue: 2 cells/lane via C-row duplication ----
#pragma unroll
        for (int j = 0; j < 2; ++j) {
            const int r = ep_r0 + j;       // acc index
            const int s = ep_s0 + j;       // seq row
            float gi = fast_sigmoid(acc0[r]);
            float gf = fast_sigmoid(acc1[r]);
            float gg = fast_tanh  (acc2[r]);
            float go = fast_sigmoid(acc3[r]);
            c_[j] = gf * c_[j] + gi * gg;
            float hh = go * fast_tanh(c_[j]);
            ((unsigned short*)&aA[nb][s][0])[u] = bf16hi_rn(hh);
            if (t == TSTEPS - 1) hf[s][u] = hh;
        }

        // ---- x-part of step t+1 (independent of h; before next barrier) ----
        if (t < TSTEPS - 1) {
            int t1 = t + 1;
            bsh8 ax = xb[(t1 >> 6) & 1][t1 & 63][row8];
            acc0 = (f32x4){bi,  bi,  bi,  bi };
            acc1 = (f32x4){bf_, bf_, bf_, bf_};
            acc2 = (f32x4){bg,  bg,  bg,  bg };
            acc3 = (f32x4){bo,  bo,  bo,  bo };
            acc0 = MFMA16(ax, b02.hi, acc0); acc0 = MFMA16(ax, b02.lo, acc0);
            acc1 = MFMA16(ax, b12.hi, acc1); acc1 = MFMA16(ax, b12.lo, acc1);
            acc2 = MFMA16(ax, b22.hi, acc2); acc2 = MFMA16(ax, b22.lo, acc2);
            acc3 = MFMA16(ax, b32.hi, acc3); acc3 = MFMA16(ax, b32.lo, acc3);
        }
    }
    __syncthreads();   // hf visible

    // ---- fused pred head: pred = leaky_relu(h @ Wd^T + bd) ----
    {
        int s   = tid & 7;
        int g32 = tid >> 3;          // 32 unit-groups of 2
        int j0  = g32 * 2;
        pf[s][g32] = hf[s][j0] * Wd[j0] + hf[s][j0 + 1] * Wd[j0 + 1];
    }
    __syncthreads();
    if (tid < SPB) {
        float sum = bd[0];
#pragma unroll
        for (int j = 0; j < 32; ++j) sum += pf[tid][j];
        float p = (sum >= 0.0f) ? sum : 0.2f * sum;
        pred[seq0 + tid] = p;
    }
}

// fused losses: every block does a 16-i rank slice; block 0 also does reg MSE
__global__ __launch_bounds__(256)
void loss_kernel(const float* __restrict__ pred,
                 const float* __restrict__ ret,
                 const int* __restrict__ mask,
                 float* __restrict__ accums) {
    __shared__ float sp[NSEQ];
    __shared__ float sg[NSEQ];
    __shared__ float sq[NSEQ];
    int tid = threadIdx.x;
    for (int idx = tid; idx < NSEQ; idx += 256) {
        sp[idx] = pred[idx];
        sg[idx] = ret[idx];
        sq[idx] = (mask[idx] != 0) ? 1.0f : 0.0f;
    }
    __syncthreads();

    if (blockIdx.x == 0) {   // regression loss partials
        float v = 0.0f, m = 0.0f;
        for (int j = tid; j < NSEQ; j += 256) {
            float mj = sq[j];
            float d  = sp[j] - sg[j];
            v += d * d * mj;
            m += mj;
        }
#pragma unroll
        for (int off = 32; off > 0; off >>= 1) {
            v += __shfl_down(v, off, 64);
            m += __shfl_down(m, off, 64);
        }
        if ((tid & 63) == 0) {
            atomicAdd(&accums[0], v);
            atomicAdd(&accums[1], m);
        }
    }

    int iloc = tid >> 4;
    int jp   = tid & 15;
    int i    = blockIdx.x * 16 + iloc;
    float pi = sp[i], gi = sg[i], qi = sq[i];
    float sum = 0.0f;
    for (int j = jp; j < NSEQ; j += 16) {
        float t = -(sp[j] - pi) * (sg[j] - gi);
        sum += fmaxf(t, 0.0f) * sq[j];
    }
    sum *= qi;
#pragma unroll
    for (int off = 32; off > 0; off >>= 1) sum += __shfl_down(sum, off, 64);
    __shared__ float wsum[4];
    if ((tid & 63) == 0) wsum[tid >> 6] = sum;
    __syncthreads();
    if (tid == 0) atomicAdd(&accums[2], wsum[0] + wsum[1] + wsum[2] + wsum[3]);
}

__global__ void final_kernel(const float* __restrict__ accums,
                             float* __restrict__ out) {
    float reg  = accums[0] / (accums[1] + 1e-8f);
    float rank = accums[2] / 16777216.0f;   // N*N
    out[NSEQ + 0] = reg + rank;
    out[NSEQ + 1] = reg;
    out[NSEQ + 2] = rank;
}

extern "C" void kernel_launch(void* const* d_in, const int* in_sizes, int n_in,
                              void* d_out, int out_size, void* d_ws, size_t ws_size,
                              hipStream_t stream) {
    const float* feat = (const float*)d_in[0];
    const float* ret  = (const float*)d_in[1];
    const int*   mask = (const int*)d_in[2];
    const float* Wih  = (const float*)d_in[3];
    const float* Whh  = (const float*)d_in[4];
    const float* bih  = (const float*)d_in[5];
    const float* bhh  = (const float*)d_in[6];
    const float* Wd   = (const float*)d_in[7];
    const float* bd   = (const float*)d_in[8];
    float* out    = (float*)d_out;
    float* accums = (float*)d_ws;            // [0..3] loss partials

    lstm_kernel<<<NSEQ / SPB, BLK, 0, stream>>>(feat, Wih, Whh, bih, bhh,
                                                Wd, bd, out, accums);
    loss_kernel<<<NSEQ / 16, 256, 0, stream>>>(out, ret, mask, accums);
    final_kernel<<<1, 1, 0, stream>>>(accums, out);
}